// Round 10
// baseline (211.475 us; speedup 1.0000x reference)
//
#include <hip/hip_runtime.h>
#include <cstdint>
#include <cmath>

typedef unsigned short BF16;
typedef __attribute__((ext_vector_type(8))) short short8;
typedef __attribute__((ext_vector_type(4))) float f32x4;
typedef __attribute__((ext_vector_type(16))) float f32x16;
typedef __attribute__((ext_vector_type(2))) unsigned int uint2v;
typedef __attribute__((ext_vector_type(4))) unsigned int uint4v;

#define S_LEN 4096
#define DMODEL 512
#define NHEAD 8
#define DHEAD 64
#define BS 2
#define NROWS (BS * NHEAD * S_LEN)  // 65536 (bh, s) rows

__device__ __forceinline__ BF16 f2bf(float f) {
  union { float f; uint32_t u; } v; v.f = f;
  uint32_t r = (v.u + 0x7FFFu + ((v.u >> 16) & 1u)) >> 16;
  return (BF16)r;
}

__device__ __forceinline__ float bf2f(short u) {
  return __uint_as_float(((unsigned)(unsigned short)u) << 16);
}

__device__ __forceinline__ unsigned cvtpk(float a, float b) {
  unsigned r;
  asm volatile("v_cvt_pk_bf16_f32 %0, %1, %2" : "=v"(r) : "v"(a), "v"(b));
  return r;
}

// value held by lane l^32 (permlane32_swap: vdst'=[lo|src_lo], vsrc'=[dst_hi|hi])
__device__ __forceinline__ float partner32(float x, int hi) {
  unsigned a = __float_as_uint(x), b = a;
  uint2v r = __builtin_amdgcn_permlane32_swap(a, b, false, false);
  return __uint_as_float(hi ? r[0] : r[1]);
}

// a' = [a_lo | b_lo], b' = [a_hi | b_hi]
__device__ __forceinline__ void pl32(unsigned &a, unsigned &b) {
  uint2v r = __builtin_amdgcn_permlane32_swap(a, b, false, false);
  a = r[0]; b = r[1];
}

__device__ __forceinline__ void gload16(const void* g, void* lds) {
  __builtin_amdgcn_global_load_lds(
      (const __attribute__((address_space(1))) void*)g,
      (__attribute__((address_space(3))) void*)lds, 16, 0, 0);
}

#define MAX3(a, b, c) fmaxf(fmaxf((a), (b)), (c))
#define CS_CONST 0.18033688011112042f  // (1/sqrt(64)) * log2(e)

// ---------------- convert x: fp32 -> bf16 ----------------
__global__ __launch_bounds__(256) void cvt_x_k(const float* __restrict__ x,
                                               BF16* __restrict__ xb) {
  int i = blockIdx.x * 256 + threadIdx.x;
  float4 v = reinterpret_cast<const float4*>(x)[i];
  ushort4 o;
  o.x = f2bf(v.x); o.y = f2bf(v.y); o.z = f2bf(v.z); o.w = f2bf(v.w);
  reinterpret_cast<ushort4*>(xb)[i] = o;
}

// ---- transpose+convert both weights: W (K x N) fp32 -> Wt (N x K) bf16, one launch ----
__global__ __launch_bounds__(256) void trw_k(const float* __restrict__ W_in,
                                             const float* __restrict__ W_out,
                                             BF16* __restrict__ wint,
                                             BF16* __restrict__ woutt) {
  __shared__ float t[32][33];
  const bool second = blockIdx.x >= 48;
  const float* W = second ? W_out : W_in;
  BF16* Wt = second ? woutt : wint;
  const int N = second ? DMODEL : 3 * DMODEL;
  const int K = DMODEL;
  int n0 = (second ? ((int)blockIdx.x - 48) : (int)blockIdx.x) * 32;
  int k0 = blockIdx.y * 32;
  int tx = threadIdx.x & 31, ty = threadIdx.x >> 5;
#pragma unroll
  for (int i = 0; i < 4; ++i)
    t[ty + 8 * i][tx] = W[(size_t)(k0 + ty + 8 * i) * N + n0 + tx];
  __syncthreads();
#pragma unroll
  for (int i = 0; i < 4; ++i)
    Wt[(size_t)(n0 + ty + 8 * i) * K + k0 + tx] = f2bf(t[tx][ty + 8 * i]);
}

// ---------------- QKV GEMM: C(128x128 tile) = A(M x 512) * Bt(N x 512)^T ----------------
// Q,K,V all written coalesced [bh][s][dh].
__global__ __launch_bounds__(256)
void gemm_qkv_k(const BF16* __restrict__ A, const BF16* __restrict__ Bt,
                const float* __restrict__ bias,
                BF16* __restrict__ Qb, BF16* __restrict__ Kb, BF16* __restrict__ Vc) {
  __shared__ BF16 As[128 * 64];
  __shared__ BF16 Bs[128 * 64];
  const int tid = threadIdx.x;
  const int l = tid & 63, w = tid >> 6;
  const int wm = w >> 1, wn = w & 1;
  const int bm = blockIdx.x, bn = blockIdx.y;
  f32x4 acc[4][4] = {};

  for (int kt = 0; kt < 512 / 64; ++kt) {
#pragma unroll
    for (int i = 0; i < 4; ++i) {
      int ldsoff = i * 4096 + w * 1024;
      int off = ldsoff + l * 16;
      int row = off >> 7;
      int slot = ((off >> 4) & 7) ^ (row & 7);
      gload16(A + (size_t)(bm * 128 + row) * 512 + kt * 64 + slot * 8,
              (char*)As + ldsoff);
      gload16(Bt + (size_t)(bn * 128 + row) * 512 + kt * 64 + slot * 8,
              (char*)Bs + ldsoff);
    }
    __syncthreads();
    const char* Ab = (const char*)As;
    const char* Bb = (const char*)Bs;
    short8 af[4][2], bfr[4][2];
#pragma unroll
    for (int mf = 0; mf < 4; ++mf)
#pragma unroll
      for (int kk = 0; kk < 2; ++kk) {
        int row = wm * 64 + mf * 16 + (l & 15);
        int slot = ((l >> 4) + 4 * kk) ^ (row & 7);
        af[mf][kk] = *(const short8*)(Ab + row * 128 + slot * 16);
      }
#pragma unroll
    for (int nf = 0; nf < 4; ++nf)
#pragma unroll
      for (int kk = 0; kk < 2; ++kk) {
        int row = wn * 64 + nf * 16 + (l & 15);
        int slot = ((l >> 4) + 4 * kk) ^ (row & 7);
        bfr[nf][kk] = *(const short8*)(Bb + row * 128 + slot * 16);
      }
    __builtin_amdgcn_s_setprio(1);
#pragma unroll
    for (int kk = 0; kk < 2; ++kk)
#pragma unroll
      for (int mf = 0; mf < 4; ++mf)
#pragma unroll
        for (int nf = 0; nf < 4; ++nf)
          acc[mf][nf] = __builtin_amdgcn_mfma_f32_16x16x32_bf16(
              af[mf][kk], bfr[nf][kk], acc[mf][nf], 0, 0, 0);
    __builtin_amdgcn_s_setprio(0);
    __syncthreads();
  }

#pragma unroll
  for (int mf = 0; mf < 4; ++mf)
#pragma unroll
    for (int nf = 0; nf < 4; ++nf)
#pragma unroll
      for (int r = 0; r < 4; ++r) {
        int row = bm * 128 + wm * 64 + mf * 16 + ((l >> 4) << 2) + r;
        int col = bn * 128 + wn * 64 + nf * 16 + (l & 15);
        float v = acc[mf][nf][r] + bias[col];
        int sec = col >> 9, nl = col & 511;
        int h = nl >> 6, dh = nl & 63;
        int b = row >> 12, s = row & 4095;
        BF16* dst = sec == 0 ? Qb : (sec == 1 ? Kb : Vc);
        dst[(((size_t)(b * NHEAD + h)) * S_LEN + s) * DHEAD + dh] = f2bf(v);
      }
}

// ---------------- transpose V: Vc[bh][s][dh] -> Vt[bh][dh][s] ----------------
__global__ __launch_bounds__(256)
void v_tr_k(const BF16* __restrict__ Vc, BF16* __restrict__ Vt) {
  __shared__ BF16 t[64][66];
  const int bh = blockIdx.y, st = blockIdx.x;
  const int tid = threadIdx.x;
  const int g = tid >> 3, c8 = (tid & 7) * 8;  // g 0..31
#pragma unroll
  for (int p = 0; p < 2; ++p) {
    int s = p * 32 + g;
    short8 v = *(const short8*)(Vc + ((size_t)bh * S_LEN + st * 64 + s) * DHEAD + c8);
#pragma unroll
    for (int j = 0; j < 8; ++j) t[s][c8 + j] = (BF16)(unsigned short)v[j];
  }
  __syncthreads();
#pragma unroll
  for (int p = 0; p < 2; ++p) {
    int dh = p * 32 + g;
    short8 o;
#pragma unroll
    for (int j = 0; j < 8; ++j) o[j] = (short)t[c8 + j][dh];
    *(short8*)(Vt + ((size_t)bh * DHEAD + dh) * S_LEN + st * 64 + c8) = o;
  }
}

// ---------------- causal flash attention: 4-way kv-split uniform blocks ----------------
// 4 waves x 32 q-rows = 128-row Q tile; KVB=64; swapped-operand 32x32 MFMA; in-lane
// softmax; P packed via cvt_pk+permlane32_swap. 4-way kv-split paired {p,31-p},
// quarter {qr,3-qr}: grid 1024 uniform blocks, 4 blocks/CU. (R7 body — ones-MFMA
// reverted: it cost +32 MFMA cy/step for ~35 VALU cy saved, measured -10us.)
__global__ __launch_bounds__(256, 4)
void attn_k(const BF16* __restrict__ Qg, const BF16* __restrict__ Kg,
            const BF16* __restrict__ Vg, BF16* __restrict__ Opb,
            float* __restrict__ Ml) {
  __shared__ BF16 Kl[2][64 * 64];
  __shared__ BF16 Vl[2][64 * 64];
  const int tid = threadIdx.x, l = tid & 63, w = tid >> 6;
  const int hi = l >> 5, ln = l & 31;
  const int wgid = blockIdx.x;
  const int xcd = wgid & 7, j = wgid >> 3;  // j 0..127
  const int bh = xcd * 2 + (j & 1);         // 2 heads per XCD (K/V L2-resident)
  const int qr = (j >> 1) & 3;              // quarter index
  const int p = j >> 3;                     // pair index 0..15
  const BF16* Qh = Qg + (size_t)bh * S_LEN * DHEAD;
  const BF16* Kh = Kg + (size_t)bh * S_LEN * DHEAD;
  const BF16* Vh = Vg + (size_t)bh * DHEAD * S_LEN;
  const float CS = CS_CONST;

  int cur = 0;
  for (int rep = 0; rep < 2; ++rep) {
    const int qt = rep ? (31 - p) : p;
    const int qq = rep ? (3 - qr) : qr;     // balanced quarter pairing
    const int NTf = 2 * qt + 2;             // full kv-range of this tile
    const int kbase = (qq * NTf) >> 2;      // quarter start
    const int kend = ((qq + 1) * NTf) >> 2; // quarter end
    const int NT = kend - kbase;            // steps this rep (can be 0)
    const int q0w = qt * 128 + w * 32;
    const int qrow = q0w + ln;
    __syncthreads();  // prior rep's reads done before restaging

    short8 qb[4];
    {
      const BF16* qp = Qh + (size_t)qrow * DHEAD + hi * 8;
#pragma unroll
      for (int ks = 0; ks < 4; ++ks) qb[ks] = *(const short8*)(qp + ks * 16);
    }
    f32x16 oacc0 = {}, oacc1 = {};
    float m_ = -INFINITY, l_ = 0.f;

    auto stage = [&](int buf, int ktile) {
      const int kv0 = ktile * 64;
#pragma unroll
      for (int i = 0; i < 2; ++i) {
        int base = i * 4096 + w * 1024;
        int off = base + l * 16;
        int row = off >> 7;
        int slot = ((off >> 4) & 7) ^ (row & 7);
        gload16(Kh + (size_t)(kv0 + row) * DHEAD + slot * 8, (char*)Kl[buf] + base);
        gload16(Vh + (size_t)row * S_LEN + kv0 + slot * 8, (char*)Vl[buf] + base);
      }
    };

    if (NT > 0) {
      stage(cur, kbase);
      for (int kt = 0; kt < NT; ++kt) {
        __syncthreads();  // buf[cur] staged; prior reads of buf[cur^1] done
        if (kt + 1 < NT) stage(cur ^ 1, kbase + kt + 1);
        const int kv0 = (kbase + kt) * 64;
        if (kv0 <= q0w + 31) {  // wave-uniform: skip fully-masked tile
          // --- QK^T: S^T[kv][q] ---
          const char* Kb_ = (const char*)Kl[cur];
          f32x16 s0 = {}, s1 = {};
          __builtin_amdgcn_s_setprio(1);
#pragma unroll
          for (int ks = 0; ks < 4; ++ks) {
            int slot0 = (2 * ks + hi) ^ (ln & 7);
            short8 kf0 = *(const short8*)(Kb_ + ln * 128 + slot0 * 16);
            int row1 = 32 + ln;
            int slot1 = (2 * ks + hi) ^ (row1 & 7);
            short8 kf1 = *(const short8*)(Kb_ + row1 * 128 + slot1 * 16);
            s0 = __builtin_amdgcn_mfma_f32_32x32x16_bf16(kf0, qb[ks], s0, 0, 0, 0);
            s1 = __builtin_amdgcn_mfma_f32_32x32x16_bf16(kf1, qb[ks], s1, 0, 0, 0);
          }
          __builtin_amdgcn_s_setprio(0);
          // --- causal mask on diagonal-overlap tiles ---
          if (kv0 + 63 > q0w) {
#pragma unroll
            for (int r = 0; r < 16; ++r) {
              int crow = (r & 3) + 8 * (r >> 2) + 4 * hi;
              if (kv0 + crow > qrow) s0[r] = -INFINITY;
              if (kv0 + 32 + crow > qrow) s1[r] = -INFINITY;
            }
          }
          // --- in-lane online softmax (v_max3 tree) ---
          float a0 = MAX3(s0[0], s0[1], s0[2]);
          float a1 = MAX3(s0[3], s0[4], s0[5]);
          float a2 = MAX3(s0[6], s0[7], s0[8]);
          float a3 = MAX3(s0[9], s0[10], s0[11]);
          float a4 = MAX3(s0[12], s0[13], s0[14]);
          float a5 = MAX3(s0[15], s1[0], s1[1]);
          float a6 = MAX3(s1[2], s1[3], s1[4]);
          float a7 = MAX3(s1[5], s1[6], s1[7]);
          float a8 = MAX3(s1[8], s1[9], s1[10]);
          float a9 = MAX3(s1[11], s1[12], s1[13]);
          float a10 = fmaxf(s1[14], s1[15]);
          float b0 = MAX3(a0, a1, a2);
          float b1 = MAX3(a3, a4, a5);
          float b2 = MAX3(a6, a7, a8);
          float b3 = fmaxf(a9, a10);
          float pmax = fmaxf(fmaxf(b0, b1), fmaxf(b2, b3));
          pmax = fmaxf(pmax, partner32(pmax, hi));
          bool need = (pmax - m_) * CS > 8.0f;  // defer-max (T13)
          if (__any(need)) {
            float mn = fmaxf(m_, pmax);
            float alpha = exp2f((m_ - mn) * CS);
            m_ = mn;
            l_ *= alpha;
#pragma unroll
            for (int r = 0; r < 16; ++r) { oacc0[r] *= alpha; oacc1[r] *= alpha; }
          }
          const float mb = m_ * CS;
          float p0[16], p1[16];
          float rs = 0.f;
#pragma unroll
          for (int r = 0; r < 16; ++r) { p0[r] = exp2f(fmaf(s0[r], CS, -mb)); rs += p0[r]; }
#pragma unroll
          for (int r = 0; r < 16; ++r) { p1[r] = exp2f(fmaf(s1[r], CS, -mb)); rs += p1[r]; }
          rs += partner32(rs, hi);
          l_ += rs;
          // --- pack P into B-fragments (T12: cvt_pk + permlane32_swap) ---
          short8 pf[4];
#pragma unroll
          for (int hf = 0; hf < 2; ++hf) {
            const float* pp = hf ? p1 : p0;
            unsigned w01 = cvtpk(pp[0], pp[1]), w23 = cvtpk(pp[2], pp[3]);
            unsigned w45 = cvtpk(pp[4], pp[5]), w67 = cvtpk(pp[6], pp[7]);
            unsigned w89 = cvtpk(pp[8], pp[9]), wab = cvtpk(pp[10], pp[11]);
            unsigned wcd = cvtpk(pp[12], pp[13]), wef = cvtpk(pp[14], pp[15]);
            pl32(w01, w45);  // w01 -> dw0 {hi0:kv01,hi1:kv89}, w45 -> dw2
            pl32(w23, w67);  // w23 -> dw1, w67 -> dw3
            pl32(w89, wcd);
            pl32(wab, wef);
            union { uint4v u; short8 s; } c0, c1;
            c0.u = (uint4v){w01, w23, w45, w67};
            c1.u = (uint4v){w89, wab, wcd, wef};
            pf[hf * 2 + 0] = c0.s;
            pf[hf * 2 + 1] = c1.s;
          }
          // --- PV: O^T[dh][q] += V^T * P^T ---
          const char* Vb_ = (const char*)Vl[cur];
          __builtin_amdgcn_s_setprio(1);
#pragma unroll
          for (int ks = 0; ks < 4; ++ks) {
            int slot0 = (2 * ks + hi) ^ (ln & 7);
            short8 vf0 = *(const short8*)(Vb_ + ln * 128 + slot0 * 16);
            int row1 = 32 + ln;
            int slot1 = (2 * ks + hi) ^ (row1 & 7);
            short8 vf1 = *(const short8*)(Vb_ + row1 * 128 + slot1 * 16);
            oacc0 = __builtin_amdgcn_mfma_f32_32x32x16_bf16(vf0, pf[ks], oacc0, 0, 0, 0);
            oacc1 = __builtin_amdgcn_mfma_f32_32x32x16_bf16(vf1, pf[ks], oacc1, 0, 0, 0);
          }
          __builtin_amdgcn_s_setprio(0);
        }
        cur ^= 1;
      }
    }

    // partial epilogue: un-normalized O (bf16) + (m,l) f32 per row, slot = quarter qq
    BF16* Op = Opb + ((size_t)qq * NROWS + (size_t)bh * S_LEN + qrow) * DHEAD;
#pragma unroll
    for (int blk = 0; blk < 2; ++blk) {
      const f32x16 oa = blk ? oacc1 : oacc0;
#pragma unroll
      for (int g = 0; g < 4; ++g) {
        int dh0 = 8 * g + 4 * hi + 32 * blk;
        unsigned lo = cvtpk(oa[4 * g + 0], oa[4 * g + 1]);
        unsigned h2 = cvtpk(oa[4 * g + 2], oa[4 * g + 3]);
        uint2v st = {lo, h2};
        *(uint2v*)(Op + dh0) = st;
      }
    }
    if (hi == 0) {
      float2 ml = {m_, l_};
      *(float2*)(Ml + ((size_t)qq * NROWS + (size_t)bh * S_LEN + qrow) * 2) = ml;
    }
  }
}

// ------- output GEMM with fused merge: out = merge(Opb,Ml) @ W_out^T + b_out -------
// K-step kt (BK=64=DHEAD) corresponds exactly to head h=kt of O. A-tile is staged
// by reading the 4 partial slots + (m,l), merging in registers, and ds_write_b128
// into the same XOR-swizzled LDS layout the fragment reader uses.
__global__ __launch_bounds__(256)
void gemm_out_k(const BF16* __restrict__ Opb, const float* __restrict__ Ml,
                const BF16* __restrict__ Bt, const float* __restrict__ bias,
                float* __restrict__ Out) {
  __shared__ BF16 As[128 * 64];
  __shared__ BF16 Bs[128 * 64];
  const int tid = threadIdx.x;
  const int l = tid & 63, w = tid >> 6;
  const int wm = w >> 1, wn = w & 1;
  const int bm = blockIdx.x, bn = blockIdx.y;
  const size_t SL = (size_t)NROWS * DHEAD;  // elements per partial slot
  f32x4 acc[4][4] = {};

  for (int kt = 0; kt < 512 / 64; ++kt) {
    // B staging (async, linear dest / inverse-swizzled source)
#pragma unroll
    for (int i = 0; i < 4; ++i) {
      int ldsoff = i * 4096 + w * 1024;
      int off = ldsoff + l * 16;
      int row = off >> 7;
      int slot = ((off >> 4) & 7) ^ (row & 7);
      gload16(Bt + (size_t)(bn * 128 + row) * 512 + kt * 64 + slot * 8,
              (char*)Bs + ldsoff);
    }
    // A staging: reg-merge of 4 partial slots, swizzled ds_write
#pragma unroll
    for (int i = 0; i < 4; ++i) {
      int off = i * 4096 + w * 1024 + l * 16;
      int row = off >> 7;               // 0..127 within tile
      int dh0 = (off & 127) >> 1;       // 0,8,..,56
      int slot16 = ((off >> 4) & 7) ^ (row & 7);
      int g = bm * 128 + row;
      int b = g >> 12, s = g & 4095;
      size_t mlb = ((size_t)(b * NHEAD + kt)) * S_LEN + s;
      size_t base = mlb * DHEAD + dh0;
      short8 v0 = *(const short8*)(Opb + base);
      short8 v1 = *(const short8*)(Opb + SL + base);
      short8 v2 = *(const short8*)(Opb + 2 * SL + base);
      short8 v3 = *(const short8*)(Opb + 3 * SL + base);
      float2 ml0 = *(const float2*)(Ml + mlb * 2);
      float2 ml1 = *(const float2*)(Ml + ((size_t)NROWS + mlb) * 2);
      float2 ml2 = *(const float2*)(Ml + ((size_t)2 * NROWS + mlb) * 2);
      float2 ml3 = *(const float2*)(Ml + ((size_t)3 * NROWS + mlb) * 2);
      float m = fmaxf(fmaxf(ml0.x, ml1.x), fmaxf(ml2.x, ml3.x));
      float a0 = exp2f((ml0.x - m) * CS_CONST);
      float a1 = exp2f((ml1.x - m) * CS_CONST);
      float a2 = exp2f((ml2.x - m) * CS_CONST);
      float a3 = exp2f((ml3.x - m) * CS_CONST);
      float linv = 1.0f / (ml0.y * a0 + ml1.y * a1 + ml2.y * a2 + ml3.y * a3);
      a0 *= linv; a1 *= linv; a2 *= linv; a3 *= linv;
      float o[8];
#pragma unroll
      for (int jj = 0; jj < 8; ++jj)
        o[jj] = bf2f(v0[jj]) * a0 + bf2f(v1[jj]) * a1 +
                bf2f(v2[jj]) * a2 + bf2f(v3[jj]) * a3;
      union { uint4v u; short8 s; } pk;
      pk.u = (uint4v){cvtpk(o[0], o[1]), cvtpk(o[2], o[3]),
                      cvtpk(o[4], o[5]), cvtpk(o[6], o[7])};
      *(short8*)((char*)As + row * 128 + slot16 * 16) = pk.s;
    }
    __syncthreads();
    const char* Ab = (const char*)As;
    const char* Bb = (const char*)Bs;
    short8 af[4][2], bfr[4][2];
#pragma unroll
    for (int mf = 0; mf < 4; ++mf)
#pragma unroll
      for (int kk = 0; kk < 2; ++kk) {
        int row = wm * 64 + mf * 16 + (l & 15);
        int slot = ((l >> 4) + 4 * kk) ^ (row & 7);
        af[mf][kk] = *(const short8*)(Ab + row * 128 + slot * 16);
      }
#pragma unroll
    for (int nf = 0; nf < 4; ++nf)
#pragma unroll
      for (int kk = 0; kk < 2; ++kk) {
        int row = wn * 64 + nf * 16 + (l & 15);
        int slot = ((l >> 4) + 4 * kk) ^ (row & 7);
        bfr[nf][kk] = *(const short8*)(Bb + row * 128 + slot * 16);
      }
    __builtin_amdgcn_s_setprio(1);
#pragma unroll
    for (int kk = 0; kk < 2; ++kk)
#pragma unroll
      for (int mf = 0; mf < 4; ++mf)
#pragma unroll
        for (int nf = 0; nf < 4; ++nf)
          acc[mf][nf] = __builtin_amdgcn_mfma_f32_16x16x32_bf16(
              af[mf][kk], bfr[nf][kk], acc[mf][nf], 0, 0, 0);
    __builtin_amdgcn_s_setprio(0);
    __syncthreads();
  }

#pragma unroll
  for (int mf = 0; mf < 4; ++mf)
#pragma unroll
    for (int nf = 0; nf < 4; ++nf)
#pragma unroll
      for (int r = 0; r < 4; ++r) {
        int row = bm * 128 + wm * 64 + mf * 16 + ((l >> 4) << 2) + r;
        int col = bn * 128 + wn * 64 + nf * 16 + (l & 15);
        Out[(size_t)row * DMODEL + col] = acc[mf][nf][r] + bias[col];
      }
}

// ---------------- launch ----------------
extern "C" void kernel_launch(void* const* d_in, const int* in_sizes, int n_in,
                              void* d_out, int out_size, void* d_ws, size_t ws_size,
                              hipStream_t stream) {
  const float* x = (const float*)d_in[0];
  const float* W_in = (const float*)d_in[1];
  const float* b_in = (const float*)d_in[2];
  const float* W_out = (const float*)d_in[3];
  const float* b_out = (const float*)d_in[4];
  float* out = (float*)d_out;

  char* ws = (char*)d_ws;
  const size_t SZ_X = (size_t)BS * S_LEN * DMODEL * 2;      // 8 MB bf16 tensor
  const size_t SZ_OP = (size_t)NROWS * DHEAD * 2;           // 8.39 MB bf16 partial/slot
  BF16* xb    = (BF16*)(ws);
  BF16* Vt    = xb;  // ALIAS: xb is dead after gemm_qkv; v_tr_k writes Vt after it
  BF16* wint  = (BF16*)(ws + SZ_X);
  BF16* woutt = (BF16*)(ws + SZ_X + 3 * DMODEL * DMODEL * 2);
  BF16* Qb    = (BF16*)(ws + SZ_X + 4 * DMODEL * DMODEL * 2);
  BF16* Kb    = (BF16*)((char*)Qb + SZ_X);
  BF16* Vc    = (BF16*)((char*)Kb + SZ_X);
  BF16* Opb   = (BF16*)((char*)Vc + SZ_X);                  // 4 slots
  float* Ml   = (float*)((char*)Opb + 4 * SZ_OP);           // 4 * NROWS * float2

  cvt_x_k<<<dim3((BS * S_LEN * DMODEL) / 4 / 256), 256, 0, stream>>>(x, xb);
  trw_k<<<dim3(64, DMODEL / 32), 256, 0, stream>>>(W_in, W_out, wint, woutt);
  gemm_qkv_k<<<dim3(BS * S_LEN / 128, 3 * DMODEL / 128), 256, 0, stream>>>(
      xb, wint, b_in, Qb, Kb, Vc);
  v_tr_k<<<dim3(S_LEN / 64, BS * NHEAD), 256, 0, stream>>>(Vc, Vt);
  attn_k<<<dim3(1024), 256, 0, stream>>>(Qb, Kb, Vt, Opb, Ml);
  gemm_out_k<<<dim3(BS * S_LEN / 128, DMODEL / 128), 256, 0, stream>>>(
      Opb, Ml, woutt, b_out, out);
}

// Round 11
// 193.713 us; speedup vs baseline: 1.0917x; 1.0917x over previous
//
#include <hip/hip_runtime.h>
#include <cstdint>
#include <cmath>

typedef unsigned short BF16;
typedef __attribute__((ext_vector_type(8))) short short8;
typedef __attribute__((ext_vector_type(4))) float f32x4;
typedef __attribute__((ext_vector_type(16))) float f32x16;
typedef __attribute__((ext_vector_type(2))) unsigned int uint2v;
typedef __attribute__((ext_vector_type(4))) unsigned int uint4v;

#define S_LEN 4096
#define DMODEL 512
#define NHEAD 8
#define DHEAD 64
#define BS 2
#define NROWS (BS * NHEAD * S_LEN)  // 65536 (bh, s) rows

__device__ __forceinline__ BF16 f2bf(float f) {
  union { float f; uint32_t u; } v; v.f = f;
  uint32_t r = (v.u + 0x7FFFu + ((v.u >> 16) & 1u)) >> 16;
  return (BF16)r;
}

__device__ __forceinline__ float bf2f(short u) {
  return __uint_as_float(((unsigned)(unsigned short)u) << 16);
}

__device__ __forceinline__ unsigned cvtpk(float a, float b) {
  unsigned r;
  asm volatile("v_cvt_pk_bf16_f32 %0, %1, %2" : "=v"(r) : "v"(a), "v"(b));
  return r;
}

// value held by lane l^32 (permlane32_swap: vdst'=[lo|src_lo], vsrc'=[dst_hi|hi])
__device__ __forceinline__ float partner32(float x, int hi) {
  unsigned a = __float_as_uint(x), b = a;
  uint2v r = __builtin_amdgcn_permlane32_swap(a, b, false, false);
  return __uint_as_float(hi ? r[0] : r[1]);
}

// a' = [a_lo | b_lo], b' = [a_hi | b_hi]
__device__ __forceinline__ void pl32(unsigned &a, unsigned &b) {
  uint2v r = __builtin_amdgcn_permlane32_swap(a, b, false, false);
  a = r[0]; b = r[1];
}

__device__ __forceinline__ void gload16(const void* g, void* lds) {
  __builtin_amdgcn_global_load_lds(
      (const __attribute__((address_space(1))) void*)g,
      (__attribute__((address_space(3))) void*)lds, 16, 0, 0);
}

#define MAX3(a, b, c) fmaxf(fmaxf((a), (b)), (c))
#define CS_CONST 0.18033688011112042f  // (1/sqrt(64)) * log2(e)

// ---------------- convert x: fp32 -> bf16 ----------------
__global__ __launch_bounds__(256) void cvt_x_k(const float* __restrict__ x,
                                               BF16* __restrict__ xb) {
  int i = blockIdx.x * 256 + threadIdx.x;
  float4 v = reinterpret_cast<const float4*>(x)[i];
  ushort4 o;
  o.x = f2bf(v.x); o.y = f2bf(v.y); o.z = f2bf(v.z); o.w = f2bf(v.w);
  reinterpret_cast<ushort4*>(xb)[i] = o;
}

// ---- transpose+convert both weights: W (K x N) fp32 -> Wt (N x K) bf16, one launch ----
__global__ __launch_bounds__(256) void trw_k(const float* __restrict__ W_in,
                                             const float* __restrict__ W_out,
                                             BF16* __restrict__ wint,
                                             BF16* __restrict__ woutt) {
  __shared__ float t[32][33];
  const bool second = blockIdx.x >= 48;
  const float* W = second ? W_out : W_in;
  BF16* Wt = second ? woutt : wint;
  const int N = second ? DMODEL : 3 * DMODEL;
  const int K = DMODEL;
  int n0 = (second ? ((int)blockIdx.x - 48) : (int)blockIdx.x) * 32;
  int k0 = blockIdx.y * 32;
  int tx = threadIdx.x & 31, ty = threadIdx.x >> 5;
#pragma unroll
  for (int i = 0; i < 4; ++i)
    t[ty + 8 * i][tx] = W[(size_t)(k0 + ty + 8 * i) * N + n0 + tx];
  __syncthreads();
#pragma unroll
  for (int i = 0; i < 4; ++i)
    Wt[(size_t)(n0 + ty + 8 * i) * K + k0 + tx] = f2bf(t[tx][ty + 8 * i]);
}

// ---------------- GEMM: C(128x128 tile) = A(M x 512) * Bt(N x 512)^T ----------------
// MODE 0: QKV projection; Q,K,V written coalesced [bh][s][dh].
// MODE 1: output projection, fp32 out.
template <int MODE>
__global__ __launch_bounds__(256)
void gemm_k(const BF16* __restrict__ A, const BF16* __restrict__ Bt,
            const float* __restrict__ bias,
            BF16* __restrict__ Qb, BF16* __restrict__ Kb, BF16* __restrict__ Vc,
            float* __restrict__ Out) {
  __shared__ BF16 As[128 * 64];
  __shared__ BF16 Bs[128 * 64];
  const int tid = threadIdx.x;
  const int l = tid & 63, w = tid >> 6;
  const int wm = w >> 1, wn = w & 1;
  const int bm = blockIdx.x, bn = blockIdx.y;
  f32x4 acc[4][4] = {};

  for (int kt = 0; kt < 512 / 64; ++kt) {
#pragma unroll
    for (int i = 0; i < 4; ++i) {
      int ldsoff = i * 4096 + w * 1024;
      int off = ldsoff + l * 16;
      int row = off >> 7;
      int slot = ((off >> 4) & 7) ^ (row & 7);
      gload16(A + (size_t)(bm * 128 + row) * 512 + kt * 64 + slot * 8,
              (char*)As + ldsoff);
      gload16(Bt + (size_t)(bn * 128 + row) * 512 + kt * 64 + slot * 8,
              (char*)Bs + ldsoff);
    }
    __syncthreads();
    const char* Ab = (const char*)As;
    const char* Bb = (const char*)Bs;
    short8 af[4][2], bfr[4][2];
#pragma unroll
    for (int mf = 0; mf < 4; ++mf)
#pragma unroll
      for (int kk = 0; kk < 2; ++kk) {
        int row = wm * 64 + mf * 16 + (l & 15);
        int slot = ((l >> 4) + 4 * kk) ^ (row & 7);
        af[mf][kk] = *(const short8*)(Ab + row * 128 + slot * 16);
      }
#pragma unroll
    for (int nf = 0; nf < 4; ++nf)
#pragma unroll
      for (int kk = 0; kk < 2; ++kk) {
        int row = wn * 64 + nf * 16 + (l & 15);
        int slot = ((l >> 4) + 4 * kk) ^ (row & 7);
        bfr[nf][kk] = *(const short8*)(Bb + row * 128 + slot * 16);
      }
    __builtin_amdgcn_s_setprio(1);
#pragma unroll
    for (int kk = 0; kk < 2; ++kk)
#pragma unroll
      for (int mf = 0; mf < 4; ++mf)
#pragma unroll
        for (int nf = 0; nf < 4; ++nf)
          acc[mf][nf] = __builtin_amdgcn_mfma_f32_16x16x32_bf16(
              af[mf][kk], bfr[nf][kk], acc[mf][nf], 0, 0, 0);
    __builtin_amdgcn_s_setprio(0);
    __syncthreads();
  }

#pragma unroll
  for (int mf = 0; mf < 4; ++mf)
#pragma unroll
    for (int nf = 0; nf < 4; ++nf)
#pragma unroll
      for (int r = 0; r < 4; ++r) {
        int row = bm * 128 + wm * 64 + mf * 16 + ((l >> 4) << 2) + r;
        int col = bn * 128 + wn * 64 + nf * 16 + (l & 15);
        float v = acc[mf][nf][r] + bias[col];
        if (MODE == 0) {
          int sec = col >> 9, nl = col & 511;
          int h = nl >> 6, dh = nl & 63;
          int b = row >> 12, s = row & 4095;
          BF16* dst = sec == 0 ? Qb : (sec == 1 ? Kb : Vc);
          dst[(((size_t)(b * NHEAD + h)) * S_LEN + s) * DHEAD + dh] = f2bf(v);
        } else {
          Out[(size_t)row * DMODEL + col] = v;
        }
      }
}

// ---------------- transpose V: Vc[bh][s][dh] -> Vt[bh][dh][s] ----------------
__global__ __launch_bounds__(256)
void v_tr_k(const BF16* __restrict__ Vc, BF16* __restrict__ Vt) {
  __shared__ BF16 t[64][66];
  const int bh = blockIdx.y, st = blockIdx.x;
  const int tid = threadIdx.x;
  const int g = tid >> 3, c8 = (tid & 7) * 8;  // g 0..31
#pragma unroll
  for (int p = 0; p < 2; ++p) {
    int s = p * 32 + g;
    short8 v = *(const short8*)(Vc + ((size_t)bh * S_LEN + st * 64 + s) * DHEAD + c8);
#pragma unroll
    for (int j = 0; j < 8; ++j) t[s][c8 + j] = (BF16)(unsigned short)v[j];
  }
  __syncthreads();
#pragma unroll
  for (int p = 0; p < 2; ++p) {
    int dh = p * 32 + g;
    short8 o;
#pragma unroll
    for (int j = 0; j < 8; ++j) o[j] = (short)t[c8 + j][dh];
    *(short8*)(Vt + ((size_t)bh * DHEAD + dh) * S_LEN + st * 64 + c8) = o;
  }
}

// ---------------- causal flash attention: 4-way kv-split uniform blocks ----------------
// 4 waves x 32 q-rows = 128-row Q tile; KVB=64; swapped-operand 32x32 MFMA; in-lane
// softmax; P packed via cvt_pk+permlane32_swap. 4-way kv-split paired {p,31-p},
// quarter {qr,3-qr}: grid 1024 uniform blocks, 4 blocks/CU. (R10 body, measured 77.5us.)
__global__ __launch_bounds__(256, 4)
void attn_k(const BF16* __restrict__ Qg, const BF16* __restrict__ Kg,
            const BF16* __restrict__ Vg, BF16* __restrict__ Opb,
            float* __restrict__ Ml) {
  __shared__ BF16 Kl[2][64 * 64];
  __shared__ BF16 Vl[2][64 * 64];
  const int tid = threadIdx.x, l = tid & 63, w = tid >> 6;
  const int hi = l >> 5, ln = l & 31;
  const int wgid = blockIdx.x;
  const int xcd = wgid & 7, j = wgid >> 3;  // j 0..127
  const int bh = xcd * 2 + (j & 1);         // 2 heads per XCD (K/V L2-resident)
  const int qr = (j >> 1) & 3;              // quarter index
  const int p = j >> 3;                     // pair index 0..15
  const BF16* Qh = Qg + (size_t)bh * S_LEN * DHEAD;
  const BF16* Kh = Kg + (size_t)bh * S_LEN * DHEAD;
  const BF16* Vh = Vg + (size_t)bh * DHEAD * S_LEN;
  const float CS = CS_CONST;

  int cur = 0;
  for (int rep = 0; rep < 2; ++rep) {
    const int qt = rep ? (31 - p) : p;
    const int qq = rep ? (3 - qr) : qr;     // balanced quarter pairing
    const int NTf = 2 * qt + 2;             // full kv-range of this tile
    const int kbase = (qq * NTf) >> 2;      // quarter start
    const int kend = ((qq + 1) * NTf) >> 2; // quarter end
    const int NT = kend - kbase;            // steps this rep (can be 0)
    const int q0w = qt * 128 + w * 32;
    const int qrow = q0w + ln;
    __syncthreads();  // prior rep's reads done before restaging

    short8 qb[4];
    {
      const BF16* qp = Qh + (size_t)qrow * DHEAD + hi * 8;
#pragma unroll
      for (int ks = 0; ks < 4; ++ks) qb[ks] = *(const short8*)(qp + ks * 16);
    }
    f32x16 oacc0 = {}, oacc1 = {};
    float m_ = -INFINITY, l_ = 0.f;

    auto stage = [&](int buf, int ktile) {
      const int kv0 = ktile * 64;
#pragma unroll
      for (int i = 0; i < 2; ++i) {
        int base = i * 4096 + w * 1024;
        int off = base + l * 16;
        int row = off >> 7;
        int slot = ((off >> 4) & 7) ^ (row & 7);
        gload16(Kh + (size_t)(kv0 + row) * DHEAD + slot * 8, (char*)Kl[buf] + base);
        gload16(Vh + (size_t)row * S_LEN + kv0 + slot * 8, (char*)Vl[buf] + base);
      }
    };

    if (NT > 0) {
      stage(cur, kbase);
      for (int kt = 0; kt < NT; ++kt) {
        __syncthreads();  // buf[cur] staged; prior reads of buf[cur^1] done
        if (kt + 1 < NT) stage(cur ^ 1, kbase + kt + 1);
        const int kv0 = (kbase + kt) * 64;
        if (kv0 <= q0w + 31) {  // wave-uniform: skip fully-masked tile
          // --- QK^T: S^T[kv][q] ---
          const char* Kb_ = (const char*)Kl[cur];
          f32x16 s0 = {}, s1 = {};
          __builtin_amdgcn_s_setprio(1);
#pragma unroll
          for (int ks = 0; ks < 4; ++ks) {
            int slot0 = (2 * ks + hi) ^ (ln & 7);
            short8 kf0 = *(const short8*)(Kb_ + ln * 128 + slot0 * 16);
            int row1 = 32 + ln;
            int slot1 = (2 * ks + hi) ^ (row1 & 7);
            short8 kf1 = *(const short8*)(Kb_ + row1 * 128 + slot1 * 16);
            s0 = __builtin_amdgcn_mfma_f32_32x32x16_bf16(kf0, qb[ks], s0, 0, 0, 0);
            s1 = __builtin_amdgcn_mfma_f32_32x32x16_bf16(kf1, qb[ks], s1, 0, 0, 0);
          }
          __builtin_amdgcn_s_setprio(0);
          // --- causal mask on diagonal-overlap tiles ---
          if (kv0 + 63 > q0w) {
#pragma unroll
            for (int r = 0; r < 16; ++r) {
              int crow = (r & 3) + 8 * (r >> 2) + 4 * hi;
              if (kv0 + crow > qrow) s0[r] = -INFINITY;
              if (kv0 + 32 + crow > qrow) s1[r] = -INFINITY;
            }
          }
          // --- in-lane online softmax (v_max3 tree) ---
          float a0 = MAX3(s0[0], s0[1], s0[2]);
          float a1 = MAX3(s0[3], s0[4], s0[5]);
          float a2 = MAX3(s0[6], s0[7], s0[8]);
          float a3 = MAX3(s0[9], s0[10], s0[11]);
          float a4 = MAX3(s0[12], s0[13], s0[14]);
          float a5 = MAX3(s0[15], s1[0], s1[1]);
          float a6 = MAX3(s1[2], s1[3], s1[4]);
          float a7 = MAX3(s1[5], s1[6], s1[7]);
          float a8 = MAX3(s1[8], s1[9], s1[10]);
          float a9 = MAX3(s1[11], s1[12], s1[13]);
          float a10 = fmaxf(s1[14], s1[15]);
          float b0 = MAX3(a0, a1, a2);
          float b1 = MAX3(a3, a4, a5);
          float b2 = MAX3(a6, a7, a8);
          float b3 = fmaxf(a9, a10);
          float pmax = fmaxf(fmaxf(b0, b1), fmaxf(b2, b3));
          pmax = fmaxf(pmax, partner32(pmax, hi));
          bool need = (pmax - m_) * CS > 8.0f;  // defer-max (T13)
          if (__any(need)) {
            float mn = fmaxf(m_, pmax);
            float alpha = exp2f((m_ - mn) * CS);
            m_ = mn;
            l_ *= alpha;
#pragma unroll
            for (int r = 0; r < 16; ++r) { oacc0[r] *= alpha; oacc1[r] *= alpha; }
          }
          const float mb = m_ * CS;
          float p0[16], p1[16];
          float rs = 0.f;
#pragma unroll
          for (int r = 0; r < 16; ++r) { p0[r] = exp2f(fmaf(s0[r], CS, -mb)); rs += p0[r]; }
#pragma unroll
          for (int r = 0; r < 16; ++r) { p1[r] = exp2f(fmaf(s1[r], CS, -mb)); rs += p1[r]; }
          rs += partner32(rs, hi);
          l_ += rs;
          // --- pack P into B-fragments (T12: cvt_pk + permlane32_swap) ---
          short8 pf[4];
#pragma unroll
          for (int hf = 0; hf < 2; ++hf) {
            const float* pp = hf ? p1 : p0;
            unsigned w01 = cvtpk(pp[0], pp[1]), w23 = cvtpk(pp[2], pp[3]);
            unsigned w45 = cvtpk(pp[4], pp[5]), w67 = cvtpk(pp[6], pp[7]);
            unsigned w89 = cvtpk(pp[8], pp[9]), wab = cvtpk(pp[10], pp[11]);
            unsigned wcd = cvtpk(pp[12], pp[13]), wef = cvtpk(pp[14], pp[15]);
            pl32(w01, w45);  // w01 -> dw0 {hi0:kv01,hi1:kv89}, w45 -> dw2
            pl32(w23, w67);  // w23 -> dw1, w67 -> dw3
            pl32(w89, wcd);
            pl32(wab, wef);
            union { uint4v u; short8 s; } c0, c1;
            c0.u = (uint4v){w01, w23, w45, w67};
            c1.u = (uint4v){w89, wab, wcd, wef};
            pf[hf * 2 + 0] = c0.s;
            pf[hf * 2 + 1] = c1.s;
          }
          // --- PV: O^T[dh][q] += V^T * P^T ---
          const char* Vb_ = (const char*)Vl[cur];
          __builtin_amdgcn_s_setprio(1);
#pragma unroll
          for (int ks = 0; ks < 4; ++ks) {
            int slot0 = (2 * ks + hi) ^ (ln & 7);
            short8 vf0 = *(const short8*)(Vb_ + ln * 128 + slot0 * 16);
            int row1 = 32 + ln;
            int slot1 = (2 * ks + hi) ^ (row1 & 7);
            short8 vf1 = *(const short8*)(Vb_ + row1 * 128 + slot1 * 16);
            oacc0 = __builtin_amdgcn_mfma_f32_32x32x16_bf16(vf0, pf[ks], oacc0, 0, 0, 0);
            oacc1 = __builtin_amdgcn_mfma_f32_32x32x16_bf16(vf1, pf[ks], oacc1, 0, 0, 0);
          }
          __builtin_amdgcn_s_setprio(0);
        }
        cur ^= 1;
      }
    }

    // partial epilogue: un-normalized O (bf16) + (m,l) f32 per row, slot = quarter qq
    BF16* Op = Opb + ((size_t)qq * NROWS + (size_t)bh * S_LEN + qrow) * DHEAD;
#pragma unroll
    for (int blk = 0; blk < 2; ++blk) {
      const f32x16 oa = blk ? oacc1 : oacc0;
#pragma unroll
      for (int g = 0; g < 4; ++g) {
        int dh0 = 8 * g + 4 * hi + 32 * blk;
        unsigned lo = cvtpk(oa[4 * g + 0], oa[4 * g + 1]);
        unsigned h2 = cvtpk(oa[4 * g + 2], oa[4 * g + 3]);
        uint2v st = {lo, h2};
        *(uint2v*)(Op + dh0) = st;
      }
    }
    if (hi == 0) {
      float2 ml = {m_, l_};
      *(float2*)(Ml + ((size_t)qq * NROWS + (size_t)bh * S_LEN + qrow) * 2) = ml;
    }
  }
}

// ---------------- merge 4 partial slots -> Ob (bf16, head-merged layout) ----------------
// 8 rows per wave-iter, 16B/lane loads. Ob[b][s][h*64+dh].
__global__ __launch_bounds__(256)
void merge_k(const BF16* __restrict__ Opb, const float* __restrict__ Ml,
             BF16* __restrict__ Ob) {
  const int wv = blockIdx.x * 4 + (threadIdx.x >> 6);  // 0..2047
  const int lane = threadIdx.x & 63;
  const int r_off = lane >> 3, c8 = (lane & 7) * 8;
#pragma unroll
  for (int it = 0; it < 4; ++it) {
    int row = wv * 32 + it * 8 + r_off;  // bh*4096 + s
    float2 ml0 = *(const float2*)(Ml + (size_t)row * 2);
    float2 ml1 = *(const float2*)(Ml + ((size_t)NROWS + row) * 2);
    float2 ml2 = *(const float2*)(Ml + ((size_t)2 * NROWS + row) * 2);
    float2 ml3 = *(const float2*)(Ml + ((size_t)3 * NROWS + row) * 2);
    float m = fmaxf(fmaxf(ml0.x, ml1.x), fmaxf(ml2.x, ml3.x));
    float a0 = exp2f((ml0.x - m) * CS_CONST);
    float a1 = exp2f((ml1.x - m) * CS_CONST);
    float a2 = exp2f((ml2.x - m) * CS_CONST);
    float a3 = exp2f((ml3.x - m) * CS_CONST);
    float linv = 1.0f / (ml0.y * a0 + ml1.y * a1 + ml2.y * a2 + ml3.y * a3);
    a0 *= linv; a1 *= linv; a2 *= linv; a3 *= linv;
    short8 v0 = *(const short8*)(Opb + ((size_t)0 * NROWS + row) * DHEAD + c8);
    short8 v1 = *(const short8*)(Opb + ((size_t)1 * NROWS + row) * DHEAD + c8);
    short8 v2 = *(const short8*)(Opb + ((size_t)2 * NROWS + row) * DHEAD + c8);
    short8 v3 = *(const short8*)(Opb + ((size_t)3 * NROWS + row) * DHEAD + c8);
    float o[8];
#pragma unroll
    for (int jj = 0; jj < 8; ++jj)
      o[jj] = bf2f(v0[jj]) * a0 + bf2f(v1[jj]) * a1 +
              bf2f(v2[jj]) * a2 + bf2f(v3[jj]) * a3;
    uint4v pk = {cvtpk(o[0], o[1]), cvtpk(o[2], o[3]),
                 cvtpk(o[4], o[5]), cvtpk(o[6], o[7])};
    int bh = row >> 12, s = row & 4095;
    *(uint4v*)(Ob + ((size_t)((bh >> 3) * S_LEN + s)) * DMODEL +
               (bh & 7) * DHEAD + c8) = pk;
  }
}

// ---------------- launch ----------------
extern "C" void kernel_launch(void* const* d_in, const int* in_sizes, int n_in,
                              void* d_out, int out_size, void* d_ws, size_t ws_size,
                              hipStream_t stream) {
  const float* x = (const float*)d_in[0];
  const float* W_in = (const float*)d_in[1];
  const float* b_in = (const float*)d_in[2];
  const float* W_out = (const float*)d_in[3];
  const float* b_out = (const float*)d_in[4];
  float* out = (float*)d_out;

  char* ws = (char*)d_ws;
  const size_t SZ_X = (size_t)BS * S_LEN * DMODEL * 2;      // 8 MB bf16 tensor
  const size_t SZ_OP = (size_t)NROWS * DHEAD * 2;           // 8.39 MB bf16 partial/slot
  BF16* xb    = (BF16*)(ws);
  BF16* Vt    = xb;  // ALIAS: xb is dead after gemm<0>; v_tr_k writes Vt after it
  BF16* wint  = (BF16*)(ws + SZ_X);
  BF16* woutt = (BF16*)(ws + SZ_X + 3 * DMODEL * DMODEL * 2);
  BF16* Qb    = (BF16*)(ws + SZ_X + 4 * DMODEL * DMODEL * 2);
  BF16* Kb    = (BF16*)((char*)Qb + SZ_X);
  BF16* Vc    = (BF16*)((char*)Kb + SZ_X);
  BF16* Ob    = (BF16*)((char*)Vc + SZ_X);
  BF16* Opb   = (BF16*)((char*)Ob + SZ_X);                  // 4 slots
  float* Ml   = (float*)((char*)Opb + 4 * SZ_OP);           // 4 * NROWS * float2

  cvt_x_k<<<dim3((BS * S_LEN * DMODEL) / 4 / 256), 256, 0, stream>>>(x, xb);
  trw_k<<<dim3(64, DMODEL / 32), 256, 0, stream>>>(W_in, W_out, wint, woutt);
  gemm_k<0><<<dim3(BS * S_LEN / 128, 3 * DMODEL / 128), 256, 0, stream>>>(
      xb, wint, b_in, Qb, Kb, Vc, nullptr);
  v_tr_k<<<dim3(S_LEN / 64, BS * NHEAD), 256, 0, stream>>>(Vc, Vt);
  attn_k<<<dim3(1024), 256, 0, stream>>>(Qb, Kb, Vt, Opb, Ml);
  merge_k<<<dim3(512), 256, 0, stream>>>(Opb, Ml, Ob);
  gemm_k<1><<<dim3(BS * S_LEN / 128, DMODEL / 128), 256, 0, stream>>>(
      Ob, woutt, b_out, nullptr, nullptr, nullptr, out);
}

// Round 12
// 187.447 us; speedup vs baseline: 1.1282x; 1.0334x over previous
//
#include <hip/hip_runtime.h>
#include <cstdint>
#include <cmath>

typedef unsigned short BF16;
typedef __attribute__((ext_vector_type(8))) short short8;
typedef __attribute__((ext_vector_type(4))) float f32x4;
typedef __attribute__((ext_vector_type(16))) float f32x16;
typedef __attribute__((ext_vector_type(2))) unsigned int uint2v;
typedef __attribute__((ext_vector_type(4))) unsigned int uint4v;

#define S_LEN 4096
#define DMODEL 512
#define NHEAD 8
#define DHEAD 64
#define BS 2
#define NROWS (BS * NHEAD * S_LEN)  // 65536 (bh, s) rows

__device__ __forceinline__ BF16 f2bf(float f) {
  union { float f; uint32_t u; } v; v.f = f;
  uint32_t r = (v.u + 0x7FFFu + ((v.u >> 16) & 1u)) >> 16;
  return (BF16)r;
}

__device__ __forceinline__ float bf2f(short u) {
  return __uint_as_float(((unsigned)(unsigned short)u) << 16);
}

__device__ __forceinline__ unsigned cvtpk(float a, float b) {
  unsigned r;
  asm volatile("v_cvt_pk_bf16_f32 %0, %1, %2" : "=v"(r) : "v"(a), "v"(b));
  return r;
}

// value held by lane l^32 (permlane32_swap: vdst'=[lo|src_lo], vsrc'=[dst_hi|hi])
__device__ __forceinline__ float partner32(float x, int hi) {
  unsigned a = __float_as_uint(x), b = a;
  uint2v r = __builtin_amdgcn_permlane32_swap(a, b, false, false);
  return __uint_as_float(hi ? r[0] : r[1]);
}

// a' = [a_lo | b_lo], b' = [a_hi | b_hi]
__device__ __forceinline__ void pl32(unsigned &a, unsigned &b) {
  uint2v r = __builtin_amdgcn_permlane32_swap(a, b, false, false);
  a = r[0]; b = r[1];
}

__device__ __forceinline__ void gload16(const void* g, void* lds) {
  __builtin_amdgcn_global_load_lds(
      (const __attribute__((address_space(1))) void*)g,
      (__attribute__((address_space(3))) void*)lds, 16, 0, 0);
}

#define MAX3(a, b, c) fmaxf(fmaxf((a), (b)), (c))
#define CS_CONST 0.18033688011112042f  // (1/sqrt(64)) * log2(e)

// ------- prep: fp32->bf16 convert of x (blocks 0..4095) + weight transposes (4096..5119) -------
__global__ __launch_bounds__(256)
void prep_k(const float* __restrict__ x, const float* __restrict__ W_in,
            const float* __restrict__ W_out, BF16* __restrict__ xb,
            BF16* __restrict__ wint, BF16* __restrict__ woutt) {
  __shared__ float t[32][33];
  const int bx = blockIdx.x;
  if (bx < 4096) {
    int i = bx * 256 + threadIdx.x;
    float4 v = reinterpret_cast<const float4*>(x)[i];
    ushort4 o;
    o.x = f2bf(v.x); o.y = f2bf(v.y); o.z = f2bf(v.z); o.w = f2bf(v.w);
    reinterpret_cast<ushort4*>(xb)[i] = o;
    return;
  }
  const int tb = bx - 4096;            // 0..1023
  const int bxx = tb & 63, byy = tb >> 6;
  const bool second = bxx >= 48;
  const float* W = second ? W_out : W_in;
  BF16* Wt = second ? woutt : wint;
  const int N = second ? DMODEL : 3 * DMODEL;
  const int K = DMODEL;
  int n0 = (second ? (bxx - 48) : bxx) * 32;
  int k0 = byy * 32;
  int tx = threadIdx.x & 31, ty = threadIdx.x >> 5;
#pragma unroll
  for (int i = 0; i < 4; ++i)
    t[ty + 8 * i][tx] = W[(size_t)(k0 + ty + 8 * i) * N + n0 + tx];
  __syncthreads();
#pragma unroll
  for (int i = 0; i < 4; ++i)
    Wt[(size_t)(n0 + ty + 8 * i) * K + k0 + tx] = f2bf(t[tx][ty + 8 * i]);
}

// ---------------- GEMM: C(128x128 tile) = A(M x 512) * Bt(N x 512)^T ----------------
// MODE 0: QKV projection; Q,K coalesced [bh][s][dh]; V transposed in-kernel to Vt[bh][dh][s].
// MODE 1: output projection, fp32 out.
template <int MODE>
__global__ __launch_bounds__(256)
void gemm_k(const BF16* __restrict__ A, const BF16* __restrict__ Bt,
            const float* __restrict__ bias,
            BF16* __restrict__ Qb, BF16* __restrict__ Kb, BF16* __restrict__ Vt,
            float* __restrict__ Out) {
  __shared__ BF16 As[128 * 64];
  __shared__ BF16 Bs[128 * 64];
  const int tid = threadIdx.x;
  const int l = tid & 63, w = tid >> 6;
  const int wm = w >> 1, wn = w & 1;
  const int bm = blockIdx.x, bn = blockIdx.y;
  f32x4 acc[4][4] = {};

  for (int kt = 0; kt < 512 / 64; ++kt) {
#pragma unroll
    for (int i = 0; i < 4; ++i) {
      int ldsoff = i * 4096 + w * 1024;
      int off = ldsoff + l * 16;
      int row = off >> 7;
      int slot = ((off >> 4) & 7) ^ (row & 7);
      gload16(A + (size_t)(bm * 128 + row) * 512 + kt * 64 + slot * 8,
              (char*)As + ldsoff);
      gload16(Bt + (size_t)(bn * 128 + row) * 512 + kt * 64 + slot * 8,
              (char*)Bs + ldsoff);
    }
    __syncthreads();
    const char* Ab = (const char*)As;
    const char* Bb = (const char*)Bs;
    short8 af[4][2], bfr[4][2];
#pragma unroll
    for (int mf = 0; mf < 4; ++mf)
#pragma unroll
      for (int kk = 0; kk < 2; ++kk) {
        int row = wm * 64 + mf * 16 + (l & 15);
        int slot = ((l >> 4) + 4 * kk) ^ (row & 7);
        af[mf][kk] = *(const short8*)(Ab + row * 128 + slot * 16);
      }
#pragma unroll
    for (int nf = 0; nf < 4; ++nf)
#pragma unroll
      for (int kk = 0; kk < 2; ++kk) {
        int row = wn * 64 + nf * 16 + (l & 15);
        int slot = ((l >> 4) + 4 * kk) ^ (row & 7);
        bfr[nf][kk] = *(const short8*)(Bb + row * 128 + slot * 16);
      }
    __builtin_amdgcn_s_setprio(1);
#pragma unroll
    for (int kk = 0; kk < 2; ++kk)
#pragma unroll
      for (int mf = 0; mf < 4; ++mf)
#pragma unroll
        for (int nf = 0; nf < 4; ++nf)
          acc[mf][nf] = __builtin_amdgcn_mfma_f32_16x16x32_bf16(
              af[mf][kk], bfr[nf][kk], acc[mf][nf], 0, 0, 0);
    __builtin_amdgcn_s_setprio(0);
    __syncthreads();
  }

  if (MODE == 0 && bn >= 8) {
    // V region: transpose 128s x (2 heads x 64dh) tile through LDS -> Vt[bh][dh][s]
    // head 0 of this block -> As, head 1 -> Bs (each 64dh x 128s bf16 = 16KB)
#pragma unroll
    for (int mf = 0; mf < 4; ++mf)
#pragma unroll
      for (int nf = 0; nf < 4; ++nf)
#pragma unroll
        for (int r = 0; r < 4; ++r) {
          int rloc = wm * 64 + mf * 16 + ((l >> 4) << 2) + r;  // s within tile
          int col = bn * 128 + wn * 64 + nf * 16 + (l & 15);
          float v = acc[mf][nf][r] + bias[col];
          int nl = col & 511;
          int hh = (nl >> 6) & 1;  // head within block pair
          int dh = nl & 63;
          BF16* T = hh ? Bs : As;
          T[dh * 128 + rloc] = f2bf(v);
        }
    __syncthreads();
    // coalesced store: 16 threads cover one dh-row's 128 s (256B)
    const int dh_grp = tid >> 4;          // 0..15
    const int soff = (tid & 15) * 8;      // elements
    const int b = bm >> 5, s0 = (bm & 31) * 128;
#pragma unroll
    for (int it = 0; it < 8; ++it) {
      int dhh = it * 16 + dh_grp;         // 0..127 (2 heads x 64)
      int head = dhh >> 6, dh = dhh & 63;
      const BF16* T = head ? Bs : As;
      short8 vv = *(const short8*)(T + dh * 128 + soff);
      int hglob = (bn - 8) * 2 + head;
      *(short8*)(Vt + (((size_t)(b * NHEAD + hglob)) * DHEAD + dh) * S_LEN +
                 s0 + soff) = vv;
    }
    return;
  }

#pragma unroll
  for (int mf = 0; mf < 4; ++mf)
#pragma unroll
    for (int nf = 0; nf < 4; ++nf)
#pragma unroll
      for (int r = 0; r < 4; ++r) {
        int row = bm * 128 + wm * 64 + mf * 16 + ((l >> 4) << 2) + r;
        int col = bn * 128 + wn * 64 + nf * 16 + (l & 15);
        float v = acc[mf][nf][r] + bias[col];
        if (MODE == 0) {
          int sec = col >> 9, nl = col & 511;
          int h = nl >> 6, dh = nl & 63;
          int b = row >> 12, s = row & 4095;
          BF16* dst = sec == 0 ? Qb : Kb;
          dst[(((size_t)(b * NHEAD + h)) * S_LEN + s) * DHEAD + dh] = f2bf(v);
        } else {
          Out[(size_t)row * DMODEL + col] = v;
        }
      }
}

// ---------------- causal flash attention: 4-way kv-split uniform blocks ----------------
// (R11 body, measured 77.5us — unchanged)
__global__ __launch_bounds__(256, 4)
void attn_k(const BF16* __restrict__ Qg, const BF16* __restrict__ Kg,
            const BF16* __restrict__ Vg, BF16* __restrict__ Opb,
            float* __restrict__ Ml) {
  __shared__ BF16 Kl[2][64 * 64];
  __shared__ BF16 Vl[2][64 * 64];
  const int tid = threadIdx.x, l = tid & 63, w = tid >> 6;
  const int hi = l >> 5, ln = l & 31;
  const int wgid = blockIdx.x;
  const int xcd = wgid & 7, j = wgid >> 3;  // j 0..127
  const int bh = xcd * 2 + (j & 1);         // 2 heads per XCD (K/V L2-resident)
  const int qr = (j >> 1) & 3;              // quarter index
  const int p = j >> 3;                     // pair index 0..15
  const BF16* Qh = Qg + (size_t)bh * S_LEN * DHEAD;
  const BF16* Kh = Kg + (size_t)bh * S_LEN * DHEAD;
  const BF16* Vh = Vg + (size_t)bh * DHEAD * S_LEN;
  const float CS = CS_CONST;

  int cur = 0;
  for (int rep = 0; rep < 2; ++rep) {
    const int qt = rep ? (31 - p) : p;
    const int qq = rep ? (3 - qr) : qr;     // balanced quarter pairing
    const int NTf = 2 * qt + 2;             // full kv-range of this tile
    const int kbase = (qq * NTf) >> 2;      // quarter start
    const int kend = ((qq + 1) * NTf) >> 2; // quarter end
    const int NT = kend - kbase;            // steps this rep (can be 0)
    const int q0w = qt * 128 + w * 32;
    const int qrow = q0w + ln;
    __syncthreads();  // prior rep's reads done before restaging

    short8 qb[4];
    {
      const BF16* qp = Qh + (size_t)qrow * DHEAD + hi * 8;
#pragma unroll
      for (int ks = 0; ks < 4; ++ks) qb[ks] = *(const short8*)(qp + ks * 16);
    }
    f32x16 oacc0 = {}, oacc1 = {};
    float m_ = -INFINITY, l_ = 0.f;

    auto stage = [&](int buf, int ktile) {
      const int kv0 = ktile * 64;
#pragma unroll
      for (int i = 0; i < 2; ++i) {
        int base = i * 4096 + w * 1024;
        int off = base + l * 16;
        int row = off >> 7;
        int slot = ((off >> 4) & 7) ^ (row & 7);
        gload16(Kh + (size_t)(kv0 + row) * DHEAD + slot * 8, (char*)Kl[buf] + base);
        gload16(Vh + (size_t)row * S_LEN + kv0 + slot * 8, (char*)Vl[buf] + base);
      }
    };

    if (NT > 0) {
      stage(cur, kbase);
      for (int kt = 0; kt < NT; ++kt) {
        __syncthreads();  // buf[cur] staged; prior reads of buf[cur^1] done
        if (kt + 1 < NT) stage(cur ^ 1, kbase + kt + 1);
        const int kv0 = (kbase + kt) * 64;
        if (kv0 <= q0w + 31) {  // wave-uniform: skip fully-masked tile
          // --- QK^T: S^T[kv][q] ---
          const char* Kb_ = (const char*)Kl[cur];
          f32x16 s0 = {}, s1 = {};
          __builtin_amdgcn_s_setprio(1);
#pragma unroll
          for (int ks = 0; ks < 4; ++ks) {
            int slot0 = (2 * ks + hi) ^ (ln & 7);
            short8 kf0 = *(const short8*)(Kb_ + ln * 128 + slot0 * 16);
            int row1 = 32 + ln;
            int slot1 = (2 * ks + hi) ^ (row1 & 7);
            short8 kf1 = *(const short8*)(Kb_ + row1 * 128 + slot1 * 16);
            s0 = __builtin_amdgcn_mfma_f32_32x32x16_bf16(kf0, qb[ks], s0, 0, 0, 0);
            s1 = __builtin_amdgcn_mfma_f32_32x32x16_bf16(kf1, qb[ks], s1, 0, 0, 0);
          }
          __builtin_amdgcn_s_setprio(0);
          // --- causal mask on diagonal-overlap tiles ---
          if (kv0 + 63 > q0w) {
#pragma unroll
            for (int r = 0; r < 16; ++r) {
              int crow = (r & 3) + 8 * (r >> 2) + 4 * hi;
              if (kv0 + crow > qrow) s0[r] = -INFINITY;
              if (kv0 + 32 + crow > qrow) s1[r] = -INFINITY;
            }
          }
          // --- in-lane online softmax (v_max3 tree) ---
          float a0 = MAX3(s0[0], s0[1], s0[2]);
          float a1 = MAX3(s0[3], s0[4], s0[5]);
          float a2 = MAX3(s0[6], s0[7], s0[8]);
          float a3 = MAX3(s0[9], s0[10], s0[11]);
          float a4 = MAX3(s0[12], s0[13], s0[14]);
          float a5 = MAX3(s0[15], s1[0], s1[1]);
          float a6 = MAX3(s1[2], s1[3], s1[4]);
          float a7 = MAX3(s1[5], s1[6], s1[7]);
          float a8 = MAX3(s1[8], s1[9], s1[10]);
          float a9 = MAX3(s1[11], s1[12], s1[13]);
          float a10 = fmaxf(s1[14], s1[15]);
          float b0 = MAX3(a0, a1, a2);
          float b1 = MAX3(a3, a4, a5);
          float b2 = MAX3(a6, a7, a8);
          float b3 = fmaxf(a9, a10);
          float pmax = fmaxf(fmaxf(b0, b1), fmaxf(b2, b3));
          pmax = fmaxf(pmax, partner32(pmax, hi));
          bool need = (pmax - m_) * CS > 8.0f;  // defer-max (T13)
          if (__any(need)) {
            float mn = fmaxf(m_, pmax);
            float alpha = exp2f((m_ - mn) * CS);
            m_ = mn;
            l_ *= alpha;
#pragma unroll
            for (int r = 0; r < 16; ++r) { oacc0[r] *= alpha; oacc1[r] *= alpha; }
          }
          const float mb = m_ * CS;
          float p0[16], p1[16];
          float rs = 0.f;
#pragma unroll
          for (int r = 0; r < 16; ++r) { p0[r] = exp2f(fmaf(s0[r], CS, -mb)); rs += p0[r]; }
#pragma unroll
          for (int r = 0; r < 16; ++r) { p1[r] = exp2f(fmaf(s1[r], CS, -mb)); rs += p1[r]; }
          rs += partner32(rs, hi);
          l_ += rs;
          // --- pack P into B-fragments (T12: cvt_pk + permlane32_swap) ---
          short8 pf[4];
#pragma unroll
          for (int hf = 0; hf < 2; ++hf) {
            const float* pp = hf ? p1 : p0;
            unsigned w01 = cvtpk(pp[0], pp[1]), w23 = cvtpk(pp[2], pp[3]);
            unsigned w45 = cvtpk(pp[4], pp[5]), w67 = cvtpk(pp[6], pp[7]);
            unsigned w89 = cvtpk(pp[8], pp[9]), wab = cvtpk(pp[10], pp[11]);
            unsigned wcd = cvtpk(pp[12], pp[13]), wef = cvtpk(pp[14], pp[15]);
            pl32(w01, w45);  // w01 -> dw0 {hi0:kv01,hi1:kv89}, w45 -> dw2
            pl32(w23, w67);  // w23 -> dw1, w67 -> dw3
            pl32(w89, wcd);
            pl32(wab, wef);
            union { uint4v u; short8 s; } c0, c1;
            c0.u = (uint4v){w01, w23, w45, w67};
            c1.u = (uint4v){w89, wab, wcd, wef};
            pf[hf * 2 + 0] = c0.s;
            pf[hf * 2 + 1] = c1.s;
          }
          // --- PV: O^T[dh][q] += V^T * P^T ---
          const char* Vb_ = (const char*)Vl[cur];
          __builtin_amdgcn_s_setprio(1);
#pragma unroll
          for (int ks = 0; ks < 4; ++ks) {
            int slot0 = (2 * ks + hi) ^ (ln & 7);
            short8 vf0 = *(const short8*)(Vb_ + ln * 128 + slot0 * 16);
            int row1 = 32 + ln;
            int slot1 = (2 * ks + hi) ^ (row1 & 7);
            short8 vf1 = *(const short8*)(Vb_ + row1 * 128 + slot1 * 16);
            oacc0 = __builtin_amdgcn_mfma_f32_32x32x16_bf16(vf0, pf[ks], oacc0, 0, 0, 0);
            oacc1 = __builtin_amdgcn_mfma_f32_32x32x16_bf16(vf1, pf[ks], oacc1, 0, 0, 0);
          }
          __builtin_amdgcn_s_setprio(0);
        }
        cur ^= 1;
      }
    }

    // partial epilogue: un-normalized O (bf16) + (m,l) f32 per row, slot = quarter qq
    BF16* Op = Opb + ((size_t)qq * NROWS + (size_t)bh * S_LEN + qrow) * DHEAD;
#pragma unroll
    for (int blk = 0; blk < 2; ++blk) {
      const f32x16 oa = blk ? oacc1 : oacc0;
#pragma unroll
      for (int g = 0; g < 4; ++g) {
        int dh0 = 8 * g + 4 * hi + 32 * blk;
        unsigned lo = cvtpk(oa[4 * g + 0], oa[4 * g + 1]);
        unsigned h2 = cvtpk(oa[4 * g + 2], oa[4 * g + 3]);
        uint2v st = {lo, h2};
        *(uint2v*)(Op + dh0) = st;
      }
    }
    if (hi == 0) {
      float2 ml = {m_, l_};
      *(float2*)(Ml + ((size_t)qq * NROWS + (size_t)bh * S_LEN + qrow) * 2) = ml;
    }
  }
}

// ---------------- merge 4 partial slots -> Ob (bf16, head-merged layout) ----------------
__global__ __launch_bounds__(256)
void merge_k(const BF16* __restrict__ Opb, const float* __restrict__ Ml,
             BF16* __restrict__ Ob) {
  const int wv = blockIdx.x * 4 + (threadIdx.x >> 6);  // 0..2047
  const int lane = threadIdx.x & 63;
  const int r_off = lane >> 3, c8 = (lane & 7) * 8;
#pragma unroll
  for (int it = 0; it < 4; ++it) {
    int row = wv * 32 + it * 8 + r_off;  // bh*4096 + s
    float2 ml0 = *(const float2*)(Ml + (size_t)row * 2);
    float2 ml1 = *(const float2*)(Ml + ((size_t)NROWS + row) * 2);
    float2 ml2 = *(const float2*)(Ml + ((size_t)2 * NROWS + row) * 2);
    float2 ml3 = *(const float2*)(Ml + ((size_t)3 * NROWS + row) * 2);
    float m = fmaxf(fmaxf(ml0.x, ml1.x), fmaxf(ml2.x, ml3.x));
    float a0 = exp2f((ml0.x - m) * CS_CONST);
    float a1 = exp2f((ml1.x - m) * CS_CONST);
    float a2 = exp2f((ml2.x - m) * CS_CONST);
    float a3 = exp2f((ml3.x - m) * CS_CONST);
    float linv = 1.0f / (ml0.y * a0 + ml1.y * a1 + ml2.y * a2 + ml3.y * a3);
    a0 *= linv; a1 *= linv; a2 *= linv; a3 *= linv;
    short8 v0 = *(const short8*)(Opb + ((size_t)0 * NROWS + row) * DHEAD + c8);
    short8 v1 = *(const short8*)(Opb + ((size_t)1 * NROWS + row) * DHEAD + c8);
    short8 v2 = *(const short8*)(Opb + ((size_t)2 * NROWS + row) * DHEAD + c8);
    short8 v3 = *(const short8*)(Opb + ((size_t)3 * NROWS + row) * DHEAD + c8);
    float o[8];
#pragma unroll
    for (int jj = 0; jj < 8; ++jj)
      o[jj] = bf2f(v0[jj]) * a0 + bf2f(v1[jj]) * a1 +
              bf2f(v2[jj]) * a2 + bf2f(v3[jj]) * a3;
    uint4v pk = {cvtpk(o[0], o[1]), cvtpk(o[2], o[3]),
                 cvtpk(o[4], o[5]), cvtpk(o[6], o[7])};
    int bh = row >> 12, s = row & 4095;
    *(uint4v*)(Ob + ((size_t)((bh >> 3) * S_LEN + s)) * DMODEL +
               (bh & 7) * DHEAD + c8) = pk;
  }
}

// ---------------- launch ----------------
extern "C" void kernel_launch(void* const* d_in, const int* in_sizes, int n_in,
                              void* d_out, int out_size, void* d_ws, size_t ws_size,
                              hipStream_t stream) {
  const float* x = (const float*)d_in[0];
  const float* W_in = (const float*)d_in[1];
  const float* b_in = (const float*)d_in[2];
  const float* W_out = (const float*)d_in[3];
  const float* b_out = (const float*)d_in[4];
  float* out = (float*)d_out;

  char* ws = (char*)d_ws;
  const size_t SZ_X = (size_t)BS * S_LEN * DMODEL * 2;      // 8 MB bf16 tensor
  const size_t SZ_OP = (size_t)NROWS * DHEAD * 2;           // 8.39 MB bf16 partial/slot
  BF16* xb    = (BF16*)(ws);
  BF16* Ob    = xb;  // ALIAS: xb dead after gemm<0>; merge_k writes Ob after attn
  BF16* wint  = (BF16*)(ws + SZ_X);
  BF16* woutt = (BF16*)(ws + SZ_X + 3 * DMODEL * DMODEL * 2);
  BF16* Qb    = (BF16*)(ws + SZ_X + 4 * DMODEL * DMODEL * 2);
  BF16* Kb    = (BF16*)((char*)Qb + SZ_X);
  BF16* Vt    = (BF16*)((char*)Kb + SZ_X);   // own buffer: written during gemm<0>
  BF16* Opb   = (BF16*)((char*)Vt + SZ_X);   // 4 slots
  float* Ml   = (float*)((char*)Opb + 4 * SZ_OP);

  prep_k<<<dim3(4096 + 1024), 256, 0, stream>>>(x, W_in, W_out, xb, wint, woutt);
  gemm_k<0><<<dim3(BS * S_LEN / 128, 3 * DMODEL / 128), 256, 0, stream>>>(
      xb, wint, b_in, Qb, Kb, Vt, nullptr);
  attn_k<<<dim3(1024), 256, 0, stream>>>(Qb, Kb, Vt, Opb, Ml);
  merge_k<<<dim3(512), 256, 0, stream>>>(Opb, Ml, Ob);
  gemm_k<1><<<dim3(BS * S_LEN / 128, DMODEL / 128), 256, 0, stream>>>(
      Ob, woutt, b_out, nullptr, nullptr, nullptr, out);
}